// Round 7
// baseline (108.031 us; speedup 1.0000x reference)
//
#include <hip/hip_runtime.h>

// LDDMM variational evolve: B=1, N=8192, D=3, fp32.
// dmom_i = 2g * (x_i * sum_j w_ij  -  sum_j w_ij x_j),  w_ij = K_ij <p_i,p_j>
// dx_i   = sum_j K_ij p_j,   K_ij = exp(-g |x_i - x_j|^2), g = 100.
//
// Round 7: eliminate the broadcast memory pipe entirely. A j-segment is 64
// points = one wave: each lane holds one pre-scaled j-point in 7 VGPRs, and
// the loop broadcasts lane l's values via v_readlane_b32 -> SGPR (each VALU
// op uses <=1 SGPR operand — legal). No ds_read, no VMEM, no s_waitcnt in
// the K-loop. History: LDS staging ~36-39us (R3/R5/R6 invariant), SMRD ~47us
// (R4). Pure-VALU floor here ~17us (256 t-iters/SIMD x ~166 cyc).

#define TPB 256
#define ITILE 4
constexpr float GAMMA_C = 100.0f;
constexpr float LOG2E_C = 1.4426950408889634f;
constexpr float SB_C    = 2.0f * GAMMA_C * LOG2E_C;  // a.xyz = SB*x_j
constexpr float SC_C    = -GAMMA_C * LOG2E_C;        // a.w   = SC*|x_j|^2
constexpr float LN2_C   = 0.69314718055994531f;      // 2g/SB

static __device__ __forceinline__ float rl(float v, int l) {
  return __int_as_float(__builtin_amdgcn_readlane(__float_as_int(v), l));
}

// ---- Kernel A: per-segment partial sums (register broadcast) ---------------
// grid (N/(TPB*ITILE), N/64). Segment seg covers j in [seg*64, seg*64+64).
// ws layout: P[c][s][i], c=0..6 (a, wx', wy', wz', gx, gy, gz), each [SEG][N].
__global__ __launch_bounds__(TPB, 4) void lddmm_partial(
    const float* __restrict__ mom, const float* __restrict__ xpt,
    float* __restrict__ ws, int N, int SEG) {
  const int tid  = threadIdx.x;
  const int lane = tid & 63;
  const int seg  = blockIdx.y;
  const int j    = seg * 64 + lane;        // this lane's j-point

  // Pre-scaled j-point in registers (7 VGPRs).
  const float bx = xpt[3*j], by = xpt[3*j+1], bz = xpt[3*j+2];
  const float ax = SB_C * bx, ay = SB_C * by, az = SB_C * bz;
  const float ac = SC_C * fmaf(bx, bx, fmaf(by, by, bz * bz));
  const float qx = mom[3*j], qy = mom[3*j+1], qz = mom[3*j+2];

  // My 4 i-points.
  const int i0 = blockIdx.x * (TPB * ITILE) + tid;
  const int i1 = i0 + TPB, i2 = i0 + 2*TPB, i3 = i0 + 3*TPB;
  const float x0 = xpt[3*i0], y0 = xpt[3*i0+1], z0 = xpt[3*i0+2];
  const float x1 = xpt[3*i1], y1 = xpt[3*i1+1], z1 = xpt[3*i1+2];
  const float x2 = xpt[3*i2], y2 = xpt[3*i2+1], z2 = xpt[3*i2+2];
  const float x3 = xpt[3*i3], y3 = xpt[3*i3+1], z3 = xpt[3*i3+2];
  const float p0x = mom[3*i0], p0y = mom[3*i0+1], p0z = mom[3*i0+2];
  const float p1x = mom[3*i1], p1y = mom[3*i1+1], p1z = mom[3*i1+2];
  const float p2x = mom[3*i2], p2y = mom[3*i2+1], p2z = mom[3*i2+2];
  const float p3x = mom[3*i3], p3y = mom[3*i3+1], p3z = mom[3*i3+2];
  const float c0 = SC_C * fmaf(x0, x0, fmaf(y0, y0, z0*z0));
  const float c1 = SC_C * fmaf(x1, x1, fmaf(y1, y1, z1*z1));
  const float c2 = SC_C * fmaf(x2, x2, fmaf(y2, y2, z2*z2));
  const float c3 = SC_C * fmaf(x3, x3, fmaf(y3, y3, z3*z3));

  float a0=0.f, wx0=0.f, wy0=0.f, wz0=0.f, gx0=0.f, gy0=0.f, gz0=0.f;
  float a1=0.f, wx1=0.f, wy1=0.f, wz1=0.f, gx1=0.f, gy1=0.f, gz1=0.f;
  float a2=0.f, wx2=0.f, wy2=0.f, wz2=0.f, gx2=0.f, gy2=0.f, gz2=0.f;
  float a3=0.f, wx3=0.f, wy3=0.f, wz3=0.f, gx3=0.f, gy3=0.f, gz3=0.f;

#pragma unroll 8
  for (int l = 0; l < 64; ++l) {
    // Broadcast lane l's j-point to SGPRs (VALU lane op, no memory).
    const float Ax = rl(ax, l), Ay = rl(ay, l), Az = rl(az, l), Aw = rl(ac, l);
    const float Px = rl(qx, l), Py = rl(qy, l), Pz = rl(qz, l);
    {
      const float arg = fmaf(Ax, x0, fmaf(Ay, y0, fmaf(Az, z0, c0 + Aw)));
      const float K   = __builtin_amdgcn_exp2f(arg);
      const float dot = fmaf(Px, p0x, fmaf(Py, p0y, Pz * p0z));
      const float w   = K * dot;
      a0 += w;
      wx0 = fmaf(w, Ax, wx0); wy0 = fmaf(w, Ay, wy0); wz0 = fmaf(w, Az, wz0);
      gx0 = fmaf(K, Px, gx0); gy0 = fmaf(K, Py, gy0); gz0 = fmaf(K, Pz, gz0);
    }
    {
      const float arg = fmaf(Ax, x1, fmaf(Ay, y1, fmaf(Az, z1, c1 + Aw)));
      const float K   = __builtin_amdgcn_exp2f(arg);
      const float dot = fmaf(Px, p1x, fmaf(Py, p1y, Pz * p1z));
      const float w   = K * dot;
      a1 += w;
      wx1 = fmaf(w, Ax, wx1); wy1 = fmaf(w, Ay, wy1); wz1 = fmaf(w, Az, wz1);
      gx1 = fmaf(K, Px, gx1); gy1 = fmaf(K, Py, gy1); gz1 = fmaf(K, Pz, gz1);
    }
    {
      const float arg = fmaf(Ax, x2, fmaf(Ay, y2, fmaf(Az, z2, c2 + Aw)));
      const float K   = __builtin_amdgcn_exp2f(arg);
      const float dot = fmaf(Px, p2x, fmaf(Py, p2y, Pz * p2z));
      const float w   = K * dot;
      a2 += w;
      wx2 = fmaf(w, Ax, wx2); wy2 = fmaf(w, Ay, wy2); wz2 = fmaf(w, Az, wz2);
      gx2 = fmaf(K, Px, gx2); gy2 = fmaf(K, Py, gy2); gz2 = fmaf(K, Pz, gz2);
    }
    {
      const float arg = fmaf(Ax, x3, fmaf(Ay, y3, fmaf(Az, z3, c3 + Aw)));
      const float K   = __builtin_amdgcn_exp2f(arg);
      const float dot = fmaf(Px, p3x, fmaf(Py, p3y, Pz * p3z));
      const float w   = K * dot;
      a3 += w;
      wx3 = fmaf(w, Ax, wx3); wy3 = fmaf(w, Ay, wy3); wz3 = fmaf(w, Az, wz3);
      gx3 = fmaf(K, Px, gx3); gy3 = fmaf(K, Py, gy3); gz3 = fmaf(K, Pz, gz3);
    }
  }

  const size_t SN = (size_t)SEG * N;
  float* p = ws + (size_t)seg * N;
  p[0*SN+i0]=a0;  p[0*SN+i1]=a1;  p[0*SN+i2]=a2;  p[0*SN+i3]=a3;
  p[1*SN+i0]=wx0; p[1*SN+i1]=wx1; p[1*SN+i2]=wx2; p[1*SN+i3]=wx3;
  p[2*SN+i0]=wy0; p[2*SN+i1]=wy1; p[2*SN+i2]=wy2; p[2*SN+i3]=wy3;
  p[3*SN+i0]=wz0; p[3*SN+i1]=wz1; p[3*SN+i2]=wz2; p[3*SN+i3]=wz3;
  p[4*SN+i0]=gx0; p[4*SN+i1]=gx1; p[4*SN+i2]=gx2; p[4*SN+i3]=gx3;
  p[5*SN+i0]=gy0; p[5*SN+i1]=gy1; p[5*SN+i2]=gy2; p[5*SN+i3]=gy3;
  p[6*SN+i0]=gz0; p[6*SN+i1]=gz1; p[6*SN+i2]=gz2; p[6*SN+i3]=gz3;
}

// ---- Kernel B: reduce over segments ----------------------------------------
__global__ __launch_bounds__(TPB) void lddmm_reduce(
    const float* __restrict__ ws, float* __restrict__ R, int N, int SEG) {
  const int i = blockIdx.x * TPB + threadIdx.x;
  const int c = blockIdx.y;
  const float* src = ws + (size_t)c * SEG * N + i;
  float s0 = 0.f, s1 = 0.f, s2 = 0.f, s3 = 0.f;
  int s = 0;
  for (; s + 4 <= SEG; s += 4) {
    s0 += src[(size_t)(s+0)*N]; s1 += src[(size_t)(s+1)*N];
    s2 += src[(size_t)(s+2)*N]; s3 += src[(size_t)(s+3)*N];
  }
  for (; s < SEG; ++s) s0 += src[(size_t)s*N];
  R[(size_t)c * N + i] = (s0 + s1) + (s2 + s3);
}

// ---- Kernel C: finalize ----------------------------------------------------
__global__ __launch_bounds__(TPB) void lddmm_finalize(
    const float* __restrict__ R, const float* __restrict__ xpt,
    float* __restrict__ out, int N) {
  const int i = blockIdx.x * TPB + threadIdx.x;
  const float A  = R[i];
  const float WX = R[(size_t)1*N+i], WY = R[(size_t)2*N+i], WZ = R[(size_t)3*N+i];
  const float GX = R[(size_t)4*N+i], GY = R[(size_t)5*N+i], GZ = R[(size_t)6*N+i];
  const float xi = xpt[3*i], yi = xpt[3*i+1], zi = xpt[3*i+2];
  const float TGA = 2.0f * GAMMA_C * A;
  out[3*i+0] = fmaf(TGA, xi, -LN2_C * WX);
  out[3*i+1] = fmaf(TGA, yi, -LN2_C * WY);
  out[3*i+2] = fmaf(TGA, zi, -LN2_C * WZ);
  out[3*N + 3*i + 0] = GX;
  out[3*N + 3*i + 1] = GY;
  out[3*N + 3*i + 2] = GZ;
}

// ---- Fallback (tiny ws): atomic single-kernel version ----------------------
__global__ __launch_bounds__(TPB) void lddmm_atomic(
    const float* __restrict__ mom, const float* __restrict__ xpt,
    float* __restrict__ out, int N) {
  const int i  = blockIdx.x * TPB + threadIdx.x;
  const int jb = blockIdx.y * TPB;
  __shared__ float4 sA[TPB], sP[TPB];
  {
    const int j = jb + threadIdx.x;
    const float bx = xpt[3*j], by = xpt[3*j+1], bz = xpt[3*j+2];
    sA[threadIdx.x] = make_float4(SB_C*bx, SB_C*by, SB_C*bz,
                                  SC_C * fmaf(bx, bx, fmaf(by, by, bz*bz)));
    sP[threadIdx.x] = make_float4(mom[3*j], mom[3*j+1], mom[3*j+2], 0.f);
  }
  __syncthreads();
  const float xi = xpt[3*i], yi = xpt[3*i+1], zi = xpt[3*i+2];
  const float pxi = mom[3*i], pyi = mom[3*i+1], pzi = mom[3*i+2];
  const float ci = SC_C * fmaf(xi, xi, fmaf(yi, yi, zi*zi));
  float a=0.f, wx=0.f, wy=0.f, wz=0.f, gx=0.f, gy=0.f, gz=0.f;
#pragma unroll 4
  for (int t = 0; t < TPB; ++t) {
    const float4 A = sA[t], P = sP[t];
    const float arg = fmaf(A.x, xi, fmaf(A.y, yi, fmaf(A.z, zi, ci + A.w)));
    const float K   = __builtin_amdgcn_exp2f(arg);
    const float dot = fmaf(P.x, pxi, fmaf(P.y, pyi, P.z * pzi));
    const float w   = K * dot;
    a += w;
    wx = fmaf(w, A.x, wx); wy = fmaf(w, A.y, wy); wz = fmaf(w, A.z, wz);
    gx = fmaf(K, P.x, gx); gy = fmaf(K, P.y, gy); gz = fmaf(K, P.z, gz);
  }
  const float TGA = 2.0f * GAMMA_C * a;
  atomicAdd(&out[3*i+0], fmaf(TGA, xi, -LN2_C * wx));
  atomicAdd(&out[3*i+1], fmaf(TGA, yi, -LN2_C * wy));
  atomicAdd(&out[3*i+2], fmaf(TGA, zi, -LN2_C * wz));
  atomicAdd(&out[3*N+3*i+0], gx);
  atomicAdd(&out[3*N+3*i+1], gy);
  atomicAdd(&out[3*N+3*i+2], gz);
}

extern "C" void kernel_launch(void* const* d_in, const int* in_sizes, int n_in,
                              void* d_out, int out_size, void* d_ws, size_t ws_size,
                              hipStream_t stream) {
  const float* mom = (const float*)d_in[0];   // setup_inputs order: mom first
  const float* xpt = (const float*)d_in[1];   // control_points second
  float* out = (float*)d_out;
  const int N = in_sizes[0] / 3;              // 8192

  const int SEG = N / 64;                     // 128: one wave's worth of j per segment
  const size_t need = (size_t)(7*SEG + 7) * (size_t)N * sizeof(float);  // ~29.6 MB

  if (need <= ws_size) {
    float* wsf = (float*)d_ws;
    float* R   = wsf + (size_t)7 * SEG * N;
    dim3 gA(N / (TPB * ITILE), SEG);          // (8, 128) = 1024 blocks, 4/CU
    lddmm_partial<<<gA, TPB, 0, stream>>>(mom, xpt, wsf, N, SEG);
    dim3 gB(N / TPB, 7);
    lddmm_reduce<<<gB, TPB, 0, stream>>>(wsf, R, N, SEG);
    lddmm_finalize<<<N / TPB, TPB, 0, stream>>>(R, xpt, out, N);
  } else {
    hipMemsetAsync(d_out, 0, (size_t)out_size * sizeof(float), stream);
    dim3 grid(N / TPB, N / TPB);
    lddmm_atomic<<<grid, TPB, 0, stream>>>(mom, xpt, out, N);
  }
}

// Round 8
// 97.961 us; speedup vs baseline: 1.1028x; 1.1028x over previous
//
#include <hip/hip_runtime.h>

// LDDMM variational evolve: B=1, N=8192, D=3, fp32.
// dmom_i = 2g * (x_i * sum_j w_ij  -  sum_j w_ij x_j),  w_ij = K_ij <p_i,p_j>
// dx_i   = sum_j K_ij p_j,   K_ij = exp(-g |x_i - x_j|^2), g = 100.
//
// Round 8: single-delta from R3 (best known, 97.0us): pack the two i-points
// into v2f lanes so the 30 scalar FMAs/iter become 15 v_pk_fma_f32.
// Everything else (SEG=128, JT=64, float4 LDS staging, grid, launch bounds)
// is byte-identical to R3. History: R4 SMRD / R6 pin+prefetch / R7 readlane
// all regressed -> the loop is instruction-ISSUE bound, not LDS-data bound.

#define TPB 256
#define ITILE 2
constexpr float GAMMA_C = 100.0f;
constexpr float LOG2E_C = 1.4426950408889634f;
constexpr float SB_C    = 2.0f * GAMMA_C * LOG2E_C;  // A.xyz = SB*x_j
constexpr float SC_C    = -GAMMA_C * LOG2E_C;        // A.w   = SC*|x_j|^2
constexpr float LN2_C   = 0.69314718055994531f;      // 2g/SB

typedef float v2f __attribute__((ext_vector_type(2)));

static __device__ __forceinline__ v2f splat2(float v) { return (v2f){v, v}; }
static __device__ __forceinline__ v2f fma2(v2f a, v2f b, v2f c) {
  return __builtin_elementwise_fma(a, b, c);   // -> v_pk_fma_f32
}

// ---- Kernel A: per-segment partial sums ------------------------------------
// grid (N/(TPB*ITILE), SEG). ws layout: P[c][s][i], c=0..6, each [SEG][N].
__global__ __launch_bounds__(TPB, 4) void lddmm_partial(
    const float* __restrict__ mom, const float* __restrict__ xpt,
    float* __restrict__ ws, int N, int SEG, int JT) {
  extern __shared__ float4 smem[];
  float4* sA = smem;        // {SB*x, SB*y, SB*z, SC*|x|^2}
  float4* sP = smem + JT;   // {px, py, pz, 0}
  const int tid = threadIdx.x;
  const int seg = blockIdx.y;

  for (int t = tid; t < JT; t += TPB) {
    const int j = seg * JT + t;
    const float bx = xpt[3*j], by = xpt[3*j+1], bz = xpt[3*j+2];
    sA[t] = make_float4(SB_C*bx, SB_C*by, SB_C*bz,
                        SC_C * fmaf(bx, bx, fmaf(by, by, bz*bz)));
    sP[t] = make_float4(mom[3*j], mom[3*j+1], mom[3*j+2], 0.f);
  }
  __syncthreads();

  const int i0 = blockIdx.x * (TPB * ITILE) + tid;
  const int i1 = i0 + TPB;

  // Two i-points packed into v2f lanes.
  const v2f xi = {xpt[3*i0],   xpt[3*i1]};
  const v2f yi = {xpt[3*i0+1], xpt[3*i1+1]};
  const v2f zi = {xpt[3*i0+2], xpt[3*i1+2]};
  const v2f px = {mom[3*i0],   mom[3*i1]};
  const v2f py = {mom[3*i0+1], mom[3*i1+1]};
  const v2f pz = {mom[3*i0+2], mom[3*i1+2]};
  const v2f ci = splat2(SC_C) * fma2(xi, xi, fma2(yi, yi, zi*zi));

  v2f a = {0,0}, wx = {0,0}, wy = {0,0}, wz = {0,0};
  v2f gx = {0,0}, gy = {0,0}, gz = {0,0};

#pragma unroll 4
  for (int t = 0; t < JT; ++t) {
    const float4 A = sA[t];   // wave-uniform -> LDS broadcast, no conflicts
    const float4 P = sP[t];
    const v2f Ax = splat2(A.x), Ay = splat2(A.y), Az = splat2(A.z);
    const v2f Px = splat2(P.x), Py = splat2(P.y), Pz = splat2(P.z);

    const v2f arg = fma2(Ax, xi, fma2(Ay, yi, fma2(Az, zi, ci + splat2(A.w))));
    v2f K;
    K.x = __builtin_amdgcn_exp2f(arg.x);       // bare v_exp_f32
    K.y = __builtin_amdgcn_exp2f(arg.y);
    const v2f dot = fma2(Px, px, fma2(Py, py, Pz * pz));
    const v2f w   = K * dot;
    a += w;
    wx = fma2(w, Ax, wx); wy = fma2(w, Ay, wy); wz = fma2(w, Az, wz);
    gx = fma2(K, Px, gx); gy = fma2(K, Py, gy); gz = fma2(K, Pz, gz);
  }

  const size_t SN = (size_t)SEG * N;
  float* p = ws + (size_t)seg * N;
  p[0*SN+i0]=a.x;  p[0*SN+i1]=a.y;
  p[1*SN+i0]=wx.x; p[1*SN+i1]=wx.y;
  p[2*SN+i0]=wy.x; p[2*SN+i1]=wy.y;
  p[3*SN+i0]=wz.x; p[3*SN+i1]=wz.y;
  p[4*SN+i0]=gx.x; p[4*SN+i1]=gx.y;
  p[5*SN+i0]=gy.x; p[5*SN+i1]=gy.y;
  p[6*SN+i0]=gz.x; p[6*SN+i1]=gz.y;
}

// ---- Kernel B: reduce over segments ----------------------------------------
__global__ __launch_bounds__(TPB) void lddmm_reduce(
    const float* __restrict__ ws, float* __restrict__ R, int N, int SEG) {
  const int i = blockIdx.x * TPB + threadIdx.x;
  const int c = blockIdx.y;
  const float* src = ws + (size_t)c * SEG * N + i;
  float s0 = 0.f, s1 = 0.f, s2 = 0.f, s3 = 0.f;
  int s = 0;
  for (; s + 4 <= SEG; s += 4) {
    s0 += src[(size_t)(s+0)*N]; s1 += src[(size_t)(s+1)*N];
    s2 += src[(size_t)(s+2)*N]; s3 += src[(size_t)(s+3)*N];
  }
  for (; s < SEG; ++s) s0 += src[(size_t)s*N];
  R[(size_t)c * N + i] = (s0 + s1) + (s2 + s3);
}

// ---- Kernel C: finalize ----------------------------------------------------
__global__ __launch_bounds__(TPB) void lddmm_finalize(
    const float* __restrict__ R, const float* __restrict__ xpt,
    float* __restrict__ out, int N) {
  const int i = blockIdx.x * TPB + threadIdx.x;
  const float A  = R[i];
  const float WX = R[(size_t)1*N+i], WY = R[(size_t)2*N+i], WZ = R[(size_t)3*N+i];
  const float GX = R[(size_t)4*N+i], GY = R[(size_t)5*N+i], GZ = R[(size_t)6*N+i];
  const float xi = xpt[3*i], yi = xpt[3*i+1], zi = xpt[3*i+2];
  const float TGA = 2.0f * GAMMA_C * A;
  out[3*i+0] = fmaf(TGA, xi, -LN2_C * WX);
  out[3*i+1] = fmaf(TGA, yi, -LN2_C * WY);
  out[3*i+2] = fmaf(TGA, zi, -LN2_C * WZ);
  out[3*N + 3*i + 0] = GX;
  out[3*N + 3*i + 1] = GY;
  out[3*N + 3*i + 2] = GZ;
}

// ---- Fallback (tiny ws): atomic single-kernel version ----------------------
__global__ __launch_bounds__(TPB) void lddmm_atomic(
    const float* __restrict__ mom, const float* __restrict__ xpt,
    float* __restrict__ out, int N) {
  const int i  = blockIdx.x * TPB + threadIdx.x;
  const int jb = blockIdx.y * TPB;
  __shared__ float4 sA[TPB], sP[TPB];
  {
    const int j = jb + threadIdx.x;
    const float bx = xpt[3*j], by = xpt[3*j+1], bz = xpt[3*j+2];
    sA[threadIdx.x] = make_float4(SB_C*bx, SB_C*by, SB_C*bz,
                                  SC_C * fmaf(bx, bx, fmaf(by, by, bz*bz)));
    sP[threadIdx.x] = make_float4(mom[3*j], mom[3*j+1], mom[3*j+2], 0.f);
  }
  __syncthreads();
  const float xi = xpt[3*i], yi = xpt[3*i+1], zi = xpt[3*i+2];
  const float pxi = mom[3*i], pyi = mom[3*i+1], pzi = mom[3*i+2];
  const float ci = SC_C * fmaf(xi, xi, fmaf(yi, yi, zi*zi));
  float a=0.f, wx=0.f, wy=0.f, wz=0.f, gx=0.f, gy=0.f, gz=0.f;
#pragma unroll 4
  for (int t = 0; t < TPB; ++t) {
    const float4 A = sA[t], P = sP[t];
    const float arg = fmaf(A.x, xi, fmaf(A.y, yi, fmaf(A.z, zi, ci + A.w)));
    const float K   = __builtin_amdgcn_exp2f(arg);
    const float dot = fmaf(P.x, pxi, fmaf(P.y, pyi, P.z * pzi));
    const float w   = K * dot;
    a += w;
    wx = fmaf(w, A.x, wx); wy = fmaf(w, A.y, wy); wz = fmaf(w, A.z, wz);
    gx = fmaf(K, P.x, gx); gy = fmaf(K, P.y, gy); gz = fmaf(K, P.z, gz);
  }
  const float TGA = 2.0f * GAMMA_C * a;
  atomicAdd(&out[3*i+0], fmaf(TGA, xi, -LN2_C * wx));
  atomicAdd(&out[3*i+1], fmaf(TGA, yi, -LN2_C * wy));
  atomicAdd(&out[3*i+2], fmaf(TGA, zi, -LN2_C * wz));
  atomicAdd(&out[3*N+3*i+0], gx);
  atomicAdd(&out[3*N+3*i+1], gy);
  atomicAdd(&out[3*N+3*i+2], gz);
}

extern "C" void kernel_launch(void* const* d_in, const int* in_sizes, int n_in,
                              void* d_out, int out_size, void* d_ws, size_t ws_size,
                              hipStream_t stream) {
  const float* mom = (const float*)d_in[0];   // setup_inputs order: mom first
  const float* xpt = (const float*)d_in[1];   // control_points second
  float* out = (float*)d_out;
  const int N = in_sizes[0] / 3;              // 8192

  auto need = [&](int s) { return (size_t)(7*s + 7) * (size_t)N * sizeof(float); };
  int SEG = 128;
  while (SEG > 2 && need(SEG) > ws_size) SEG >>= 1;

  if (need(SEG) <= ws_size) {
    const int JT = N / SEG;                   // 64 @ SEG=128
    float* wsf = (float*)d_ws;
    float* R   = wsf + (size_t)7 * SEG * N;
    const size_t shmem = (size_t)JT * 2 * sizeof(float4);
    dim3 gA(N / (TPB * ITILE), SEG);          // (16, 128) = 2048 blocks
    lddmm_partial<<<gA, TPB, shmem, stream>>>(mom, xpt, wsf, N, SEG, JT);
    dim3 gB(N / TPB, 7);
    lddmm_reduce<<<gB, TPB, 0, stream>>>(wsf, R, N, SEG);
    lddmm_finalize<<<N / TPB, TPB, 0, stream>>>(R, xpt, out, N);
  } else {
    hipMemsetAsync(d_out, 0, (size_t)out_size * sizeof(float), stream);
    dim3 grid(N / TPB, N / TPB);
    lddmm_atomic<<<grid, TPB, 0, stream>>>(mom, xpt, out, N);
  }
}